// Round 7
// baseline (185.650 us; speedup 1.0000x reference)
//
#include <hip/hip_runtime.h>

typedef unsigned int u32;
typedef unsigned long long u64;
typedef unsigned short u16;

#define NL 2048

typedef __attribute__((ext_vector_type(8))) short bf16x8;
typedef __attribute__((ext_vector_type(16))) float f32x16;

__device__ __forceinline__ u16 to_bf16(float f) {
  u32 b = __float_as_uint(f);
  b += 0x7FFFu + ((b >> 16) & 1u);
  return (u16)(b >> 16);
}

__device__ __forceinline__ void gload_lds16(const void* g, void* l) {
  __builtin_amdgcn_global_load_lds(
      (const __attribute__((address_space(1))) u32*)g,
      (__attribute__((address_space(3))) u32*)l, 16, 0, 0);
}

__device__ __forceinline__ u64 shfl_xor64(u64 v, int m) {
  int lo = __shfl_xor((int)(u32)v, m, 64);
  int hi = __shfl_xor((int)(u32)(v >> 32), m, 64);
  return ((u64)(u32)hi << 32) | (u32)lo;
}

// full ascending bitonic sort of 64 u32 across the wave (1 per lane)
__device__ __forceinline__ u32 sort64_u32(u32 v, int lane) {
#pragma unroll
  for (int k = 2; k <= 64; k <<= 1) {
#pragma unroll
    for (int j = k >> 1; j > 0; j >>= 1) {
      u32 p = (u32)__shfl_xor((int)v, j, 64);
      bool lower = ((lane & j) == 0);
      bool asc = ((lane & k) == 0);
      u32 lo = v < p ? v : p;
      u32 hi = v < p ? p : v;
      v = (lower == asc) ? lo : hi;
    }
  }
  return v;
}

// full ascending bitonic sort of 64 u64 across the wave (1 per lane)
__device__ __forceinline__ u64 sort64_u64(u64 v, int lane) {
#pragma unroll
  for (int k = 2; k <= 64; k <<= 1) {
#pragma unroll
    for (int j = k >> 1; j > 0; j >>= 1) {
      u64 p = shfl_xor64(v, j);
      bool lower = ((lane & j) == 0);
      bool asc = ((lane & k) == 0);
      u64 lo = v < p ? v : p;
      u64 hi = v < p ? p : v;
      v = (lower == asc) ? lo : hi;
    }
  }
  return v;
}

// ---------------------------------------------------------------------------
// Kernel A+P: exact 32-NN + weight prep. grid = 2059 x 512 threads
// (bx<2048: knn; 2048-2057: opW transpose; 2058: embW transpose + packing).
// knn: threshold T0 (32nd smallest of 64 lane-minima) -> ballot-compact
// (E[cnt]~44) -> in-register 64-u64 bitonic sort, lanes 0..31 = result.
// ---------------------------------------------------------------------------
__global__ __launch_bounds__(512) void knn_prep_kernel(
    const float* __restrict__ frames, int* __restrict__ idx32,
    const float* __restrict__ opW, const float* __restrict__ embW,
    const float* __restrict__ betaW, const float* __restrict__ sattW,
    const float* __restrict__ cattW, const float* __restrict__ nodW,
    const float* __restrict__ betaB, const float* __restrict__ sattB,
    const float* __restrict__ cattB, const float* __restrict__ nodB,
    u16* __restrict__ opWt, u16* __restrict__ embWt, float* __restrict__ w5,
    float* __restrict__ b5) {
  __shared__ union U {
    struct {
      float4 cand[2048];
      u64 comp[8][256];
    } k;
    float tp[128 * 73];
  } sm;
  const int bx = blockIdx.x;
  const int tid = threadIdx.x;

  if (bx >= 2048) {
    if (bx < 2058) {
      const int k0 = (bx - 2048) * 64;
#pragma unroll
      for (int j = 0; j < 4; j++) {
        int f = tid + j * 512;
        int kk = f >> 5;
        int o4 = (f & 31) * 4;
        float4 v = *(const float4*)(opW + (size_t)(k0 + kk) * 128 + o4);
        sm.tp[(o4 + 0) * 73 + kk] = v.x;
        sm.tp[(o4 + 1) * 73 + kk] = v.y;
        sm.tp[(o4 + 2) * 73 + kk] = v.z;
        sm.tp[(o4 + 3) * 73 + kk] = v.w;
      }
      __syncthreads();
      u32* ow = (u32*)opWt;
#pragma unroll
      for (int j = 0; j < 8; j++) {
        int f = tid + j * 512;
        int o = f >> 5, q = f & 31;
        float lo = sm.tp[o * 73 + q * 2];
        float hi = sm.tp[o * 73 + q * 2 + 1];
        ow[o * 320 + (k0 >> 1) + q] = (u32)to_bf16(lo) | ((u32)to_bf16(hi) << 16);
      }
    } else {
      for (int f = tid; f < 4096; f += 512) {
        int j = f >> 7, kk = f & 127;
        embWt[f] = to_bf16(embW[(size_t)kk * 32 + j]);
      }
      if (tid < 160) {
        int h = tid >> 5, j = tid & 31;
        float v = (h == 0) ? betaW[j]
                  : (h == 1) ? sattW[j]
                  : (h == 2) ? cattW[j]
                  : (h == 3) ? nodW[j * 2]
                             : nodW[j * 2 + 1];
        w5[j * 8 + h] = v;
      } else if (tid < 165) {
        int h = tid - 160;
        float v = (h == 0) ? betaB[0]
                  : (h == 1) ? sattB[0]
                  : (h == 2) ? cattB[0]
                  : (h == 3) ? nodB[0]
                             : nodB[1];
        b5[h] = v;
      }
    }
    return;
  }

  const int w = tid >> 6, lane = tid & 63;
  const int query = bx * 8 + w;
  const int b = query >> 11, lq = query & (NL - 1);

#pragma unroll
  for (int i = 0; i < 4; i++) {
    int l = tid + i * 512;
    const float* fp = frames + (size_t)(b * NL + l) * 12;
    float4 fr = *(const float4*)fp;
    sm.k.cand[l] = make_float4(fr.x, fr.y, fr.z,
                               fr.x * fr.x + fr.y * fr.y + fr.z * fr.z);
  }
  __syncthreads();

  float4 me = sm.k.cand[lq];
  u32 k[32];
  u32 m = 0xFFFFFFFFu;
#pragma unroll
  for (int i = 0; i < 32; i++) {
    float4 c = sm.k.cand[i * 64 + lane];
    float dot = c.x * me.x + c.y * me.y + c.z * me.z;
    float d2 = (me.w + c.w) - 2.0f * dot;
    u32 kb = __float_as_uint(d2);
    u32 key = kb ^ ((u32)((int)kb >> 31) | 0x80000000u);
    k[i] = key;
    m = key < m ? key : m;
  }

  u32 ms = sort64_u32(m, lane);
  u32 T0 = (u32)__shfl((int)ms, 31, 64);

  int base = 0;
#pragma unroll
  for (int i = 0; i < 32; i++) {
    bool flag = (k[i] <= T0);
    u64 mask = __ballot(flag);
    if (flag) {
      u32 rank = __builtin_amdgcn_mbcnt_hi(
          (u32)(mask >> 32), __builtin_amdgcn_mbcnt_lo((u32)mask, 0u));
      int pos = base + (int)rank;
      if (pos < 256) sm.k.comp[w][pos] = ((u64)k[i] << 32) | (u32)(i * 64 + lane);
    }
    base += (int)__popcll(mask);
  }
  int cnt = base < 256 ? base : 256;
  __syncthreads();  // uniform: orders in-wave LDS writes before reads

  if (cnt <= 64) {
    // pad to 64, one entry per lane, in-register bitonic sort via shuffles.
    int pz = cnt + lane;
    if (pz < 64) sm.k.comp[w][pz] = ~0ull;
    u64 e0 = sm.k.comp[w][lane];
    u64 s = sort64_u64(e0, lane);
    if (lane < 32)
      idx32[(size_t)query * 32 + lane] = (int)(s & 0xFFFFFFFFull);
  } else {
    // generic exact path; ~never taken
    for (int b0 = 0; b0 < cnt; b0 += 64) {
      bool live = (b0 + lane < cnt);
      u64 e = live ? sm.k.comp[w][b0 + lane] : ~0ull;
      int r = 0;
      for (int mi = 0; mi < cnt; mi++) {
        u64 em = sm.k.comp[w][mi];
        r += (em < e) ? 1 : 0;
      }
      if (live && r < 32)
        idx32[(size_t)query * 32 + r] = (int)(e & 0xFFFFFFFFull);
    }
  }
}

// ---------------------------------------------------------------------------
// Kernel B: stage-1 coords + gaussians + outer product -> bf16 outer[p][640]
// block = 256 (4 points x 64 lanes), grid = 4096.
// Attr loads spread across all 64 lanes (lane = (n, quad)); coords on 16.
// ---------------------------------------------------------------------------
__global__ __launch_bounds__(256) void stage1_kernel(
    const float* __restrict__ frames, const float* __restrict__ attrs,
    const int* __restrict__ aaidx, const float* __restrict__ cen1,
    const float* __restrict__ prec1, const int* __restrict__ idx32,
    u16* __restrict__ outer) {
  __shared__ float sCoord[4 * 16 * 8];
  __shared__ float sAttrT[4 * 20 * 16];  // [pt][h][n]
  __shared__ float sG1T[4 * 32 * 17];    // [pt][g][n], pitch 17
  const int tid = threadIdx.x;
  const int pt = tid >> 6, lane = tid & 63;
  const int pid = blockIdx.x * 4 + pt;
  const int b = pid >> 11;
  const int g = lane & 31;

  float pr[7][7], cn[7];
#pragma unroll
  for (int d = 0; d < 7; d++) {
    cn[d] = cen1[d * 32 + g];
#pragma unroll
    for (int kk = 0; kk < 7; kk++) pr[d][kk] = prec1[(d * 7 + kk) * 32 + g];
  }

  // attr staging: lane = (nn, q); quad q of neighbor nn (+ quad 4 on q==3)
  {
    const int nn = lane >> 2, q = lane & 3;
    int j2 = idx32[pid * 32 + nn];
    int jg2 = b * NL + j2;
    const float* ar = attrs + (size_t)jg2 * 20;
    float4 v = *(const float4*)(ar + q * 4);
    float* aw = sAttrT + pt * 320 + nn;
    aw[(q * 4 + 0) * 16] = v.x;
    aw[(q * 4 + 1) * 16] = v.y;
    aw[(q * 4 + 2) * 16] = v.z;
    aw[(q * 4 + 3) * 16] = v.w;
    if (q == 3) {
      float4 v4 = *(const float4*)(ar + 16);
      aw[16 * 16] = v4.x;
      aw[17 * 16] = v4.y;
      aw[18 * 16] = v4.z;
      aw[19 * 16] = v4.w;
    }
  }

  if (lane < 16) {
    int n = lane;
    int j = idx32[pid * 32 + n];
    int jg = b * NL + j;
    const float* fs = frames + (size_t)pid * 12;
    const float* fj = frames + (size_t)jg * 12;
    float4 A0 = *(const float4*)(fs);
    float4 A1 = *(const float4*)(fs + 4);
    float4 A2 = *(const float4*)(fs + 8);
    float4 B0 = *(const float4*)(fj);
    float4 B2 = *(const float4*)(fj + 8);
    float dx = B0.x - A0.x, dy = B0.y - A0.y, dzc = B0.z - A0.z;
    float a0x = A0.w, a0y = A1.x, a0z = A1.y;
    float a1x = A1.z, a1y = A1.w, a1z = A2.x;
    float a2x = A2.y, a2y = A2.z, a2z = A2.w;  // z_i == axes[2]
    float zjx = B2.y, zjy = B2.z, zjz = B2.w;
    float dd = dx * dx + dy * dy + dzc * dzc + 1e-12f;
    float dist = sqrtf(dd);
    float e0 = dx * a0x + dy * a0y + dzc * a0z;
    float e1 = dx * a1x + dy * a1y + dzc * a1z;
    float e2 = dx * a2x + dy * a2y + dzc * a2z;
    float zz = a2x * zjx + a2y * zjy + a2z * zjz;
    float dzv = (dx * zjx + dy * zjy + dzc * zjz) / dist;
    float zdv = (a2x * dx + a2y * dy + a2z * dzc) / dist;
    float si = (float)aaidx[pid];
    float sj = (float)aaidx[jg];
    float idist = fminf(fabsf(sj - si), 8.0f);
    float* cr = sCoord + pt * 128 + n * 8;
    cr[0] = e0; cr[1] = e1; cr[2] = e2; cr[3] = idist;
    cr[4] = zz; cr[5] = dzv; cr[6] = zdv;
  }
  __syncthreads();
  {
    const int nh = lane >> 5;
#pragma unroll
    for (int i = 0; i < 8; i++) {
      int n = nh * 8 + i;
      const float* cr = sCoord + pt * 128 + n * 8;
      float df[7];
#pragma unroll
      for (int d = 0; d < 7; d++) df[d] = cr[d] - cn[d];
      float s = 0.0f;
#pragma unroll
      for (int kk = 0; kk < 7; kk++) {
        float y = 0.0f;
#pragma unroll
        for (int d = 0; d < 7; d++) y = fmaf(df[d], pr[d][kk], y);
        s = fmaf(y, y, s);
      }
      sG1T[pt * 544 + g * 17 + n] = __expf(-0.5f * s);
    }
  }
  __syncthreads();
  {
    const int hg = lane >> 5;
    float g16[16];
#pragma unroll
    for (int n = 0; n < 16; n++) g16[n] = sG1T[pt * 544 + g * 17 + n];
    u32* orow = (u32*)(outer + (size_t)pid * 640) + (g * 20 + hg * 10) / 2;
#pragma unroll
    for (int i = 0; i < 5; i++) {
      int h0 = hg * 10 + i * 2, h1 = h0 + 1;
      float a0 = 0.f, a1 = 0.f;
#pragma unroll
      for (int c = 0; c < 4; c++) {
        float4 v0 = *(float4*)&sAttrT[pt * 320 + h0 * 16 + c * 4];
        float4 v1 = *(float4*)&sAttrT[pt * 320 + h1 * 16 + c * 4];
        a0 = fmaf(v0.x, g16[c * 4 + 0], a0);
        a0 = fmaf(v0.y, g16[c * 4 + 1], a0);
        a0 = fmaf(v0.z, g16[c * 4 + 2], a0);
        a0 = fmaf(v0.w, g16[c * 4 + 3], a0);
        a1 = fmaf(v1.x, g16[c * 4 + 0], a1);
        a1 = fmaf(v1.y, g16[c * 4 + 1], a1);
        a1 = fmaf(v1.z, g16[c * 4 + 2], a1);
        a1 = fmaf(v1.w, g16[c * 4 + 3], a1);
      }
      orow[i] = (u32)to_bf16(a0) | ((u32)to_bf16(a1) << 16);
    }
  }
}

// ---------------------------------------------------------------------------
// Kernel C: bf16 MFMA GEMM, full-K single-barrier variant.  [validated r4]
// grid = 512 (tile 32 points x 128 outs), block = 256 (4 waves).
// head8 layout per point: [catt, nf0, nf1, -, beta, satt, -, -]
// ---------------------------------------------------------------------------
__global__ __launch_bounds__(256) void gemm_kernel(
    const u16* __restrict__ outer,  // [16384][640] bf16
    const u16* __restrict__ opWt,   // [128][640] bf16 (o-major)
    const float* __restrict__ opB,
    const u16* __restrict__ embWt,  // [32][128] bf16 (j-major)
    const float* __restrict__ embB,
    const float* __restrict__ w5,   // [32][8] packed head weights
    const float* __restrict__ b5,   // [8] head biases
    float* __restrict__ head8) {
  __shared__ char smem[40960];
  const int tid = threadIdx.x;
  const int w = tid >> 6, lane = tid & 63;
  const int p0 = blockIdx.x * 32;
  const int lr = lane >> 3, lc = lane & 7;
  const int gsw = lc ^ lr;  // swizzled fetch group for A staging
  const int m = lane & 31, kh = lane >> 5;

  f32x16 acc;
#pragma unroll
  for (int r = 0; r < 16; r++) acc[r] = 0.f;

  const u16* gA = outer + (size_t)(p0 + w * 8 + lr) * 640 + gsw * 8;
#pragma unroll
  for (int cc = 0; cc < 10; cc++)
    gload_lds16(gA + cc * 64, smem + cc * 4096 + w * 1024);
  __syncthreads();

  const u16* gB = opWt + (size_t)(w * 32 + m) * 640;
#pragma unroll
  for (int cc = 0; cc < 10; cc++) {
#pragma unroll
    for (int s = 0; s < 4; s++) {
      int pg = (s * 2 + kh) ^ (m & 7);
      bf16x8 av = *(bf16x8*)(smem + cc * 4096 + m * 128 + pg * 16);
      bf16x8 bv = *(const bf16x8*)(gB + cc * 64 + s * 16 + kh * 8);
      acc = __builtin_amdgcn_mfma_f32_32x32x16_bf16(av, bv, acc, 0, 0, 0);
    }
  }
  __syncthreads();  // all waves done reading A before fTile overwrites it

  // ---- epilogue: bias+relu -> bf16 fTile (smem 0..8192, swizzled) ----
  const int o = w * 32 + m;
  float bo = opB[o];
#pragma unroll
  for (int i = 0; i < 2; i++) {
    int j = w * 8 + i * 4 + (lane >> 4);
    int ge = (lane & 15) ^ (j & 7);
    gload_lds16(embWt + j * 128 + ge * 8, smem + 8192 + w * 2048 + i * 1024);
  }
  u16* sFb = (u16*)smem;
#pragma unroll
  for (int r = 0; r < 16; r++) {
    int mm = (r & 3) + 8 * (r >> 2) + 4 * kh;
    float v = fmaxf(acc[r] + bo, 0.f);
    int pg = (o >> 3) ^ (mm & 7);
    sFb[mm * 128 + pg * 8 + (o & 7)] = to_bf16(v);
  }
  __syncthreads();

  f32x16 acc2;
#pragma unroll
  for (int r = 0; r < 16; r++) acc2[r] = 0.f;
#pragma unroll
  for (int t2 = 0; t2 < 2; t2++) {
    int gg = (w * 2 + t2) * 2 + kh;
    int pg = gg ^ (m & 7);
    bf16x8 av = *(bf16x8*)(smem + m * 256 + pg * 16);
    bf16x8 bv = *(bf16x8*)(smem + 8192 + m * 256 + pg * 16);
    acc2 = __builtin_amdgcn_mfma_f32_32x32x16_bf16(av, bv, acc2, 0, 0, 0);
  }
  float* scr = (float*)(smem + 16384) + w * 1024;
#pragma unroll
  for (int r = 0; r < 16; r++) {
    int mm = (r & 3) + 8 * (r >> 2) + 4 * kh;
    scr[mm * 32 + m] = acc2[r];
  }
  __syncthreads();

  {
    float* sc = (float*)(smem + 16384);
    int i4 = tid * 4;
    float4 v0 = *(float4*)(sc + i4);
    float4 v1 = *(float4*)(sc + 1024 + i4);
    float4 v2 = *(float4*)(sc + 2048 + i4);
    float4 v3 = *(float4*)(sc + 3072 + i4);
    int pp = tid >> 3, j0 = (tid & 7) * 4;
    float4 eb = *(const float4*)(embB + j0);
    float4 e;
    e.x = fmaxf(v0.x + v1.x + v2.x + v3.x + eb.x, 0.f);
    e.y = fmaxf(v0.y + v1.y + v2.y + v3.y + eb.y, 0.f);
    e.z = fmaxf(v0.z + v1.z + v2.z + v3.z + eb.z, 0.f);
    e.w = fmaxf(v0.w + v1.w + v2.w + v3.w + eb.w, 0.f);
    *(float4*)((float*)smem + pp * 36 + j0) = e;
  }
  __syncthreads();

  if (tid < 160) {
    int h = tid >> 5, p = tid & 31;
    const float* sE = (const float*)smem + p * 36;
    float a = b5[h];
#pragma unroll
    for (int j = 0; j < 32; j++) a = fmaf(sE[j], w5[j * 8 + h], a);
    a = fmaxf(a, 0.f);
    int slot = (h < 2) ? (h + 4) : (h - 2);
    head8[(size_t)(p0 + p) * 8 + slot] = a;
  }
}

// ---------------------------------------------------------------------------
// Kernel E: stage-2, 8 points/block (32 lanes per point) — all phases
// fully lane-utilized. block = 256, grid = 2048.
// ---------------------------------------------------------------------------
__global__ __launch_bounds__(256) void stage2_kernel(
    const float* __restrict__ frames, const int* __restrict__ aaidx,
    const float* __restrict__ cen2, const float* __restrict__ prec2,
    const float* __restrict__ emb2W, const float* __restrict__ emb2B,
    const int* __restrict__ idx32, const float* __restrict__ head8,
    float* __restrict__ out) {
  __shared__ float sCoord[8 * 32 * 5];
  __shared__ float sG2[8 * 32 * 33];
  const int tid = threadIdx.x;
  const int pt = tid >> 5, n = tid & 31;  // 8 pts x 32 lanes
  const int pid = blockIdx.x * 8 + pt;
  const int b = pid >> 11;
  const int g = n;  // lane's gaussian in the G2 phase

  float pr[5][5], cn[5];
#pragma unroll
  for (int d = 0; d < 5; d++) {
    cn[d] = cen2[d * 32 + g];
#pragma unroll
    for (int kk = 0; kk < 5; kk++) pr[d][kk] = prec2[(d * 5 + kk) * 32 + g];
  }

  // coord phase: lane = neighbor n (all 32 lanes active per point)
  float4 hv;
  float betaS, sattS;
  {
    int j = idx32[pid * 32 + n];
    int jg = b * NL + j;
    const float* fs = frames + (size_t)pid * 12;
    const float* fj = frames + (size_t)jg * 12;
    float4 A0 = *(const float4*)(fs);
    float4 A2 = *(const float4*)(fs + 8);
    float4 B0 = *(const float4*)(fj);
    float4 B2 = *(const float4*)(fj + 8);
    float dx = B0.x - A0.x, dy = B0.y - A0.y, dzc = B0.z - A0.z;
    float a2x = A2.y, a2y = A2.z, a2z = A2.w;  // z_i
    float zjx = B2.y, zjy = B2.z, zjz = B2.w;
    float dd = dx * dx + dy * dy + dzc * dzc + 1e-12f;
    float dist = sqrtf(dd);
    float zz = a2x * zjx + a2y * zjy + a2z * zjz;
    float dzv = (dx * zjx + dy * zjy + dzc * zjz) / dist;
    float zdv = (a2x * dx + a2y * dy + a2z * dzc) / dist;
    float si = (float)aaidx[pid];
    float sj = (float)aaidx[jg];
    float idist = fminf(fabsf(sj - si), 8.0f);
    float* cr = sCoord + pt * 160 + n * 5;
    cr[0] = dist; cr[1] = zz; cr[2] = dzv; cr[3] = zdv; cr[4] = idist;
    hv = *(const float4*)(head8 + (size_t)jg * 8);  // catt, nf0, nf1
    betaS = head8[(size_t)pid * 8 + 4];
    sattS = head8[(size_t)pid * 8 + 5];
  }
  __syncthreads();
  // gaussian phase: lane = gaussian g, covers all 32 neighbors of its point
  {
#pragma unroll 8
    for (int i = 0; i < 32; i++) {
      const float* cr = sCoord + pt * 160 + i * 5;
      float df[5];
#pragma unroll
      for (int d = 0; d < 5; d++) df[d] = cr[d] - cn[d];
      float s = 0.0f;
#pragma unroll
      for (int kk = 0; kk < 5; kk++) {
        float y = 0.0f;
#pragma unroll
        for (int d = 0; d < 5; d++) y = fmaf(df[d], pr[d][kk], y);
        s = fmaf(y, y, s);
      }
      sG2[pt * 1056 + i * 33 + g] = __expf(-0.5f * s);
    }
  }
  __syncthreads();
  // gw + softmax: lane = neighbor n; shfl_xor d<32 stays within the 32-half
  {
    float gw = emb2B[0];
#pragma unroll 8
    for (int gg = 0; gg < 32; gg++)
      gw = fmaf(sG2[pt * 1056 + n * 33 + gg], emb2W[gg], gw);
    gw = fmaxf(gw, 0.0f);
    float e = (n == 0) ? sattS : hv.x;
    float logit = betaS * e;
    float mx = logit;
#pragma unroll
    for (int d = 1; d < 32; d <<= 1) mx = fmaxf(mx, __shfl_xor(mx, d, 64));
    float wv = gw * __expf(logit - mx);
    float S = wv;
#pragma unroll
    for (int d = 1; d < 32; d <<= 1) S += __shfl_xor(S, d, 64);
    float a = wv / (S + 1e-6f);
    float o0 = a * hv.y, o1 = a * hv.z;
#pragma unroll
    for (int d = 1; d < 32; d <<= 1) {
      o0 += __shfl_xor(o0, d, 64);
      o1 += __shfl_xor(o1, d, 64);
    }
    if (n == 0) {
      out[pid * 2 + 0] = o0;
      out[pid * 2 + 1] = o1;
    }
  }
}

// ---------------------------------------------------------------------------
extern "C" void kernel_launch(void* const* d_in, const int* in_sizes, int n_in,
                              void* d_out, int out_size, void* d_ws, size_t ws_size,
                              hipStream_t stream) {
  const float* attrs = (const float*)d_in[0];
  const float* frames = (const float*)d_in[1];
  const int* aaidx = (const int*)d_in[2];
  const float* cen1 = (const float*)d_in[3];
  const float* prec1 = (const float*)d_in[4];
  const float* opW = (const float*)d_in[5];
  const float* opB = (const float*)d_in[6];
  const float* embW = (const float*)d_in[7];
  const float* embB = (const float*)d_in[8];
  const float* betaW = (const float*)d_in[9];
  const float* betaB = (const float*)d_in[10];
  const float* sattW = (const float*)d_in[11];
  const float* sattB = (const float*)d_in[12];
  const float* cattW = (const float*)d_in[13];
  const float* cattB = (const float*)d_in[14];
  const float* nodW = (const float*)d_in[15];
  const float* nodB = (const float*)d_in[16];
  const float* cen2 = (const float*)d_in[17];
  const float* prec2 = (const float*)d_in[18];
  const float* emb2W = (const float*)d_in[19];
  const float* emb2B = (const float*)d_in[20];
  float* out = (float*)d_out;

  char* ws = (char*)d_ws;
  int* idx32 = (int*)ws;                              // 2 MiB
  u16* outer_bf = (u16*)(ws + 2097152);               // 16384*640*2 = 20 MiB
  float* head8 = (float*)(ws + 23068672);             // 512 KiB
  u16* opWt = (u16*)(ws + 23592960);                  // 160 KiB
  u16* embWt = (u16*)(ws + 23756800);                 // 8 KiB
  float* w5 = (float*)(ws + 23764992);                // 1 KiB
  float* b5 = (float*)(ws + 23766016);                // 32 B

  knn_prep_kernel<<<dim3(2059), dim3(512), 0, stream>>>(
      frames, idx32, opW, embW, betaW, sattW, cattW, nodW, betaB, sattB,
      cattB, nodB, opWt, embWt, w5, b5);
  stage1_kernel<<<dim3(4096), dim3(256), 0, stream>>>(frames, attrs, aaidx, cen1,
                                                      prec1, idx32, outer_bf);
  gemm_kernel<<<dim3(512), dim3(256), 0, stream>>>(outer_bf, opWt, opB, embWt,
                                                   embB, w5, b5, head8);
  stage2_kernel<<<dim3(2048), dim3(256), 0, stream>>>(frames, aaidx, cen2, prec2,
                                                      emb2W, emb2B, idx32, head8, out);
}

// Round 8
// 184.319 us; speedup vs baseline: 1.0072x; 1.0072x over previous
//
#include <hip/hip_runtime.h>

typedef unsigned int u32;
typedef unsigned long long u64;
typedef unsigned short u16;

#define NL 2048

typedef __attribute__((ext_vector_type(8))) short bf16x8;
typedef __attribute__((ext_vector_type(16))) float f32x16;

__device__ __forceinline__ u16 to_bf16(float f) {
  u32 b = __float_as_uint(f);
  b += 0x7FFFu + ((b >> 16) & 1u);
  return (u16)(b >> 16);
}

__device__ __forceinline__ void gload_lds16(const void* g, void* l) {
  __builtin_amdgcn_global_load_lds(
      (const __attribute__((address_space(1))) u32*)g,
      (__attribute__((address_space(3))) u32*)l, 16, 0, 0);
}

__device__ __forceinline__ u64 shfl_xor64(u64 v, int m) {
  int lo = __shfl_xor((int)(u32)v, m, 64);
  int hi = __shfl_xor((int)(u32)(v >> 32), m, 64);
  return ((u64)(u32)hi << 32) | (u32)lo;
}

// full ascending bitonic sort of 64 u32 across the wave (1 per lane)
__device__ __forceinline__ u32 sort64_u32(u32 v, int lane) {
#pragma unroll
  for (int k = 2; k <= 64; k <<= 1) {
#pragma unroll
    for (int j = k >> 1; j > 0; j >>= 1) {
      u32 p = (u32)__shfl_xor((int)v, j, 64);
      bool lower = ((lane & j) == 0);
      bool asc = ((lane & k) == 0);
      u32 lo = v < p ? v : p;
      u32 hi = v < p ? p : v;
      v = (lower == asc) ? lo : hi;
    }
  }
  return v;
}

// full ascending bitonic sort of 64 u64 across the wave (1 per lane)
__device__ __forceinline__ u64 sort64_u64(u64 v, int lane) {
#pragma unroll
  for (int k = 2; k <= 64; k <<= 1) {
#pragma unroll
    for (int j = k >> 1; j > 0; j >>= 1) {
      u64 p = shfl_xor64(v, j);
      bool lower = ((lane & j) == 0);
      bool asc = ((lane & k) == 0);
      u64 lo = v < p ? v : p;
      u64 hi = v < p ? p : v;
      v = (lower == asc) ? lo : hi;
    }
  }
  return v;
}

// ---------------------------------------------------------------------------
// Kernel A+B+P: fused exact 32-NN + stage-1 + weight prep.
// grid = 2059 x 512 (bx<2048: knn+stage1, one wave per query/point;
// 2048-2057: opW transpose; 2058: embW transpose + head packing).
// Per wave: knn (threshold+compact+register bitonic sort) -> neighbor idx
// lands in registers -> idxw LDS -> stage-1 coords/gaussians/outer -> bf16
// outer row. No global barrier between knn and stage1; VALU-heavy stage1
// overlaps LDS-heavy knn across co-resident blocks.
// ---------------------------------------------------------------------------
__global__ __launch_bounds__(512) void knn_s1_prep_kernel(
    const float* __restrict__ frames, const float* __restrict__ attrs,
    const int* __restrict__ aaidx, const float* __restrict__ cen1,
    const float* __restrict__ prec1, int* __restrict__ idx32,
    u16* __restrict__ outer,
    const float* __restrict__ opW, const float* __restrict__ embW,
    const float* __restrict__ betaW, const float* __restrict__ sattW,
    const float* __restrict__ cattW, const float* __restrict__ nodW,
    const float* __restrict__ betaB, const float* __restrict__ sattB,
    const float* __restrict__ cattB, const float* __restrict__ nodB,
    u16* __restrict__ opWt, u16* __restrict__ embWt, float* __restrict__ w5,
    float* __restrict__ b5) {
  __shared__ union U {
    struct {
      float4 cand[2048];
      u64 comp[8][256];
    } k;
    float tp[128 * 73];
  } sm;
  const int bx = blockIdx.x;
  const int tid = threadIdx.x;

  if (bx >= 2048) {
    if (bx < 2058) {
      const int k0 = (bx - 2048) * 64;
#pragma unroll
      for (int j = 0; j < 4; j++) {
        int f = tid + j * 512;
        int kk = f >> 5;
        int o4 = (f & 31) * 4;
        float4 v = *(const float4*)(opW + (size_t)(k0 + kk) * 128 + o4);
        sm.tp[(o4 + 0) * 73 + kk] = v.x;
        sm.tp[(o4 + 1) * 73 + kk] = v.y;
        sm.tp[(o4 + 2) * 73 + kk] = v.z;
        sm.tp[(o4 + 3) * 73 + kk] = v.w;
      }
      __syncthreads();
      u32* ow = (u32*)opWt;
#pragma unroll
      for (int j = 0; j < 8; j++) {
        int f = tid + j * 512;
        int o = f >> 5, q = f & 31;
        float lo = sm.tp[o * 73 + q * 2];
        float hi = sm.tp[o * 73 + q * 2 + 1];
        ow[o * 320 + (k0 >> 1) + q] = (u32)to_bf16(lo) | ((u32)to_bf16(hi) << 16);
      }
    } else {
      for (int f = tid; f < 4096; f += 512) {
        int j = f >> 7, kk = f & 127;
        embWt[f] = to_bf16(embW[(size_t)kk * 32 + j]);
      }
      if (tid < 160) {
        int h = tid >> 5, j = tid & 31;
        float v = (h == 0) ? betaW[j]
                  : (h == 1) ? sattW[j]
                  : (h == 2) ? cattW[j]
                  : (h == 3) ? nodW[j * 2]
                             : nodW[j * 2 + 1];
        w5[j * 8 + h] = v;
      } else if (tid < 165) {
        int h = tid - 160;
        float v = (h == 0) ? betaB[0]
                  : (h == 1) ? sattB[0]
                  : (h == 2) ? cattB[0]
                  : (h == 3) ? nodB[0]
                             : nodB[1];
        b5[h] = v;
      }
    }
    return;
  }

  const int w = tid >> 6, lane = tid & 63;
  const int query = bx * 8 + w;
  const int b = query >> 11, lq = query & (NL - 1);

  // per-wave stage-1 scratch, reusing the comp region after the sort.
  // wave w: [w*1920, w*1920+1920) bytes within the 16 KB comp area.
  // (own-wave overlap with comp[w] only — verified: w*1920+1792 >= w*2048
  //  for w<=14, so idxw stays inside comp[w]; sCoord/sAttrT writes happen
  //  after the post-sort __syncthreads.)
  char* wb = (char*)&sm + 32768 + w * 1920;
  float* sCoord = (float*)wb;          // 128 floats
  float* sAttrT = sCoord + 128;        // 320 floats [h][n]
  u32* idxw = (u32*)(sAttrT + 320);    // 32 u32

  // ---- knn phase (validated r7) ----
#pragma unroll
  for (int i = 0; i < 4; i++) {
    int l = tid + i * 512;
    const float* fp = frames + (size_t)(b * NL + l) * 12;
    float4 fr = *(const float4*)fp;
    sm.k.cand[l] = make_float4(fr.x, fr.y, fr.z,
                               fr.x * fr.x + fr.y * fr.y + fr.z * fr.z);
  }
  __syncthreads();

  float4 me = sm.k.cand[lq];
  u32 k[32];
  u32 m = 0xFFFFFFFFu;
#pragma unroll
  for (int i = 0; i < 32; i++) {
    float4 c = sm.k.cand[i * 64 + lane];
    float dot = c.x * me.x + c.y * me.y + c.z * me.z;
    float d2 = (me.w + c.w) - 2.0f * dot;
    u32 kb = __float_as_uint(d2);
    u32 key = kb ^ ((u32)((int)kb >> 31) | 0x80000000u);
    k[i] = key;
    m = key < m ? key : m;
  }

  u32 ms = sort64_u32(m, lane);
  u32 T0 = (u32)__shfl((int)ms, 31, 64);

  int base = 0;
#pragma unroll
  for (int i = 0; i < 32; i++) {
    bool flag = (k[i] <= T0);
    u64 mask = __ballot(flag);
    if (flag) {
      u32 rank = __builtin_amdgcn_mbcnt_hi(
          (u32)(mask >> 32), __builtin_amdgcn_mbcnt_lo((u32)mask, 0u));
      int pos = base + (int)rank;
      if (pos < 256) sm.k.comp[w][pos] = ((u64)k[i] << 32) | (u32)(i * 64 + lane);
    }
    base += (int)__popcll(mask);
  }
  int cnt = base < 256 ? base : 256;
  __syncthreads();  // uniform: orders in-wave LDS writes before reads

  if (cnt <= 64) {
    int pz = cnt + lane;
    if (pz < 64) sm.k.comp[w][pz] = ~0ull;
    u64 e0 = sm.k.comp[w][lane];
    u64 s = sort64_u64(e0, lane);
    if (lane < 32) {
      u32 jn = (u32)(s & 0xFFFFFFFFull);
      idx32[(size_t)query * 32 + lane] = (int)jn;
      idxw[lane] = jn;
    }
  } else {
    for (int b0 = 0; b0 < cnt; b0 += 64) {
      bool live = (b0 + lane < cnt);
      u64 e = live ? sm.k.comp[w][b0 + lane] : ~0ull;
      int r = 0;
      for (int mi = 0; mi < cnt; mi++) {
        u64 em = sm.k.comp[w][mi];
        r += (em < e) ? 1 : 0;
      }
      if (live && r < 32) {
        u32 jn = (u32)(e & 0xFFFFFFFFull);
        idx32[(size_t)query * 32 + r] = (int)jn;
        idxw[r] = jn;
      }
    }
  }
  __syncthreads();  // all comp reads done; idxw visible; comp region now free

  // ---- stage-1 phase (validated r7 math, idx from idxw) ----
  const int pid = query;
  const int g = lane & 31, nh = lane >> 5;

  // attr staging: lane = (nn, q); quad q of neighbor nn (+ quad 4 on q==3)
  {
    const int nn = lane >> 2, q = lane & 3;
    int jg2 = b * NL + (int)idxw[nn];
    const float* ar = attrs + (size_t)jg2 * 20;
    float4 v = *(const float4*)(ar + q * 4);
    float* aw = sAttrT + nn;
    aw[(q * 4 + 0) * 16] = v.x;
    aw[(q * 4 + 1) * 16] = v.y;
    aw[(q * 4 + 2) * 16] = v.z;
    aw[(q * 4 + 3) * 16] = v.w;
    if (q == 3) {
      float4 v4 = *(const float4*)(ar + 16);
      aw[16 * 16] = v4.x;
      aw[17 * 16] = v4.y;
      aw[18 * 16] = v4.z;
      aw[19 * 16] = v4.w;
    }
  }
  if (lane < 16) {
    int n = lane;
    int jg = b * NL + (int)idxw[n];
    const float* fs = frames + (size_t)pid * 12;
    const float* fj = frames + (size_t)jg * 12;
    float4 A0 = *(const float4*)(fs);
    float4 A1 = *(const float4*)(fs + 4);
    float4 A2 = *(const float4*)(fs + 8);
    float4 B0 = *(const float4*)(fj);
    float4 B2 = *(const float4*)(fj + 8);
    float dx = B0.x - A0.x, dy = B0.y - A0.y, dzc = B0.z - A0.z;
    float a0x = A0.w, a0y = A1.x, a0z = A1.y;
    float a1x = A1.z, a1y = A1.w, a1z = A2.x;
    float a2x = A2.y, a2y = A2.z, a2z = A2.w;  // z_i == axes[2]
    float zjx = B2.y, zjy = B2.z, zjz = B2.w;
    float dd = dx * dx + dy * dy + dzc * dzc + 1e-12f;
    float dist = sqrtf(dd);
    float e0 = dx * a0x + dy * a0y + dzc * a0z;
    float e1 = dx * a1x + dy * a1y + dzc * a1z;
    float e2 = dx * a2x + dy * a2y + dzc * a2z;
    float zz = a2x * zjx + a2y * zjy + a2z * zjz;
    float dzv = (dx * zjx + dy * zjy + dzc * zjz) / dist;
    float zdv = (a2x * dx + a2y * dy + a2z * dzc) / dist;
    float si = (float)aaidx[pid];
    float sj = (float)aaidx[jg];
    float idist = fminf(fabsf(sj - si), 8.0f);
    float* cr = sCoord + n * 8;
    cr[0] = e0; cr[1] = e1; cr[2] = e2; cr[3] = idist;
    cr[4] = zz; cr[5] = dzv; cr[6] = zdv;
  }
  __syncthreads();

  // gaussians: lane (g, nh) computes n = nh*8..+8; exchange with pair lane
  float g16[16];
  {
    float pr[7][7], cn[7];
#pragma unroll
    for (int d = 0; d < 7; d++) {
      cn[d] = cen1[d * 32 + g];
#pragma unroll
      for (int kk = 0; kk < 7; kk++) pr[d][kk] = prec1[(d * 7 + kk) * 32 + g];
    }
    float gv[8];
#pragma unroll
    for (int i = 0; i < 8; i++) {
      int n = nh * 8 + i;
      const float* cr = sCoord + n * 8;
      float df[7];
#pragma unroll
      for (int d = 0; d < 7; d++) df[d] = cr[d] - cn[d];
      float s = 0.0f;
#pragma unroll
      for (int kk = 0; kk < 7; kk++) {
        float y = 0.0f;
#pragma unroll
        for (int d = 0; d < 7; d++) y = fmaf(df[d], pr[d][kk], y);
        s = fmaf(y, y, s);
      }
      gv[i] = __expf(-0.5f * s);
    }
#pragma unroll
    for (int i = 0; i < 8; i++) {
      float ov = __shfl_xor(gv[i], 32, 64);
      g16[i] = nh ? ov : gv[i];
      g16[8 + i] = nh ? gv[i] : ov;
    }
  }

  // outer product: lane (g, hg=nh) handles h = nh*10..+10 (r7 order)
  {
    const int hg = nh;
    u32* orow = (u32*)(outer + (size_t)pid * 640) + (g * 20 + hg * 10) / 2;
#pragma unroll
    for (int i = 0; i < 5; i++) {
      int h0 = hg * 10 + i * 2, h1 = h0 + 1;
      float a0 = 0.f, a1 = 0.f;
#pragma unroll
      for (int c = 0; c < 4; c++) {
        float4 v0 = *(float4*)&sAttrT[h0 * 16 + c * 4];
        float4 v1 = *(float4*)&sAttrT[h1 * 16 + c * 4];
        a0 = fmaf(v0.x, g16[c * 4 + 0], a0);
        a0 = fmaf(v0.y, g16[c * 4 + 1], a0);
        a0 = fmaf(v0.z, g16[c * 4 + 2], a0);
        a0 = fmaf(v0.w, g16[c * 4 + 3], a0);
        a1 = fmaf(v1.x, g16[c * 4 + 0], a1);
        a1 = fmaf(v1.y, g16[c * 4 + 1], a1);
        a1 = fmaf(v1.z, g16[c * 4 + 2], a1);
        a1 = fmaf(v1.w, g16[c * 4 + 3], a1);
      }
      orow[i] = (u32)to_bf16(a0) | ((u32)to_bf16(a1) << 16);
    }
  }
}

// ---------------------------------------------------------------------------
// Kernel C: bf16 MFMA GEMM, full-K single-barrier variant.  [validated r4]
// grid = 512 (tile 32 points x 128 outs), block = 256 (4 waves).
// head8 layout per point: [catt, nf0, nf1, -, beta, satt, -, -]
// ---------------------------------------------------------------------------
__global__ __launch_bounds__(256) void gemm_kernel(
    const u16* __restrict__ outer,  // [16384][640] bf16
    const u16* __restrict__ opWt,   // [128][640] bf16 (o-major)
    const float* __restrict__ opB,
    const u16* __restrict__ embWt,  // [32][128] bf16 (j-major)
    const float* __restrict__ embB,
    const float* __restrict__ w5,   // [32][8] packed head weights
    const float* __restrict__ b5,   // [8] head biases
    float* __restrict__ head8) {
  __shared__ char smem[40960];
  const int tid = threadIdx.x;
  const int w = tid >> 6, lane = tid & 63;
  const int p0 = blockIdx.x * 32;
  const int lr = lane >> 3, lc = lane & 7;
  const int gsw = lc ^ lr;  // swizzled fetch group for A staging
  const int m = lane & 31, kh = lane >> 5;

  f32x16 acc;
#pragma unroll
  for (int r = 0; r < 16; r++) acc[r] = 0.f;

  const u16* gA = outer + (size_t)(p0 + w * 8 + lr) * 640 + gsw * 8;
#pragma unroll
  for (int cc = 0; cc < 10; cc++)
    gload_lds16(gA + cc * 64, smem + cc * 4096 + w * 1024);
  __syncthreads();

  const u16* gB = opWt + (size_t)(w * 32 + m) * 640;
#pragma unroll
  for (int cc = 0; cc < 10; cc++) {
#pragma unroll
    for (int s = 0; s < 4; s++) {
      int pg = (s * 2 + kh) ^ (m & 7);
      bf16x8 av = *(bf16x8*)(smem + cc * 4096 + m * 128 + pg * 16);
      bf16x8 bv = *(const bf16x8*)(gB + cc * 64 + s * 16 + kh * 8);
      acc = __builtin_amdgcn_mfma_f32_32x32x16_bf16(av, bv, acc, 0, 0, 0);
    }
  }
  __syncthreads();  // all waves done reading A before fTile overwrites it

  // ---- epilogue: bias+relu -> bf16 fTile (smem 0..8192, swizzled) ----
  const int o = w * 32 + m;
  float bo = opB[o];
#pragma unroll
  for (int i = 0; i < 2; i++) {
    int j = w * 8 + i * 4 + (lane >> 4);
    int ge = (lane & 15) ^ (j & 7);
    gload_lds16(embWt + j * 128 + ge * 8, smem + 8192 + w * 2048 + i * 1024);
  }
  u16* sFb = (u16*)smem;
#pragma unroll
  for (int r = 0; r < 16; r++) {
    int mm = (r & 3) + 8 * (r >> 2) + 4 * kh;
    float v = fmaxf(acc[r] + bo, 0.f);
    int pg = (o >> 3) ^ (mm & 7);
    sFb[mm * 128 + pg * 8 + (o & 7)] = to_bf16(v);
  }
  __syncthreads();

  f32x16 acc2;
#pragma unroll
  for (int r = 0; r < 16; r++) acc2[r] = 0.f;
#pragma unroll
  for (int t2 = 0; t2 < 2; t2++) {
    int gg = (w * 2 + t2) * 2 + kh;
    int pg = gg ^ (m & 7);
    bf16x8 av = *(bf16x8*)(smem + m * 256 + pg * 16);
    bf16x8 bv = *(bf16x8*)(smem + 8192 + m * 256 + pg * 16);
    acc2 = __builtin_amdgcn_mfma_f32_32x32x16_bf16(av, bv, acc2, 0, 0, 0);
  }
  float* scr = (float*)(smem + 16384) + w * 1024;
#pragma unroll
  for (int r = 0; r < 16; r++) {
    int mm = (r & 3) + 8 * (r >> 2) + 4 * kh;
    scr[mm * 32 + m] = acc2[r];
  }
  __syncthreads();

  {
    float* sc = (float*)(smem + 16384);
    int i4 = tid * 4;
    float4 v0 = *(float4*)(sc + i4);
    float4 v1 = *(float4*)(sc + 1024 + i4);
    float4 v2 = *(float4*)(sc + 2048 + i4);
    float4 v3 = *(float4*)(sc + 3072 + i4);
    int pp = tid >> 3, j0 = (tid & 7) * 4;
    float4 eb = *(const float4*)(embB + j0);
    float4 e;
    e.x = fmaxf(v0.x + v1.x + v2.x + v3.x + eb.x, 0.f);
    e.y = fmaxf(v0.y + v1.y + v2.y + v3.y + eb.y, 0.f);
    e.z = fmaxf(v0.z + v1.z + v2.z + v3.z + eb.z, 0.f);
    e.w = fmaxf(v0.w + v1.w + v2.w + v3.w + eb.w, 0.f);
    *(float4*)((float*)smem + pp * 36 + j0) = e;
  }
  __syncthreads();

  if (tid < 160) {
    int h = tid >> 5, p = tid & 31;
    const float* sE = (const float*)smem + p * 36;
    float a = b5[h];
#pragma unroll
    for (int j = 0; j < 32; j++) a = fmaf(sE[j], w5[j * 8 + h], a);
    a = fmaxf(a, 0.f);
    int slot = (h < 2) ? (h + 4) : (h - 2);
    head8[(size_t)(p0 + p) * 8 + slot] = a;
  }
}

// ---------------------------------------------------------------------------
// Kernel E: stage-2, 8 points/block (32 lanes per point). [validated r7]
// block = 256, grid = 2048.
// ---------------------------------------------------------------------------
__global__ __launch_bounds__(256) void stage2_kernel(
    const float* __restrict__ frames, const int* __restrict__ aaidx,
    const float* __restrict__ cen2, const float* __restrict__ prec2,
    const float* __restrict__ emb2W, const float* __restrict__ emb2B,
    const int* __restrict__ idx32, const float* __restrict__ head8,
    float* __restrict__ out) {
  __shared__ float sCoord[8 * 32 * 5];
  __shared__ float sG2[8 * 32 * 33];
  const int tid = threadIdx.x;
  const int pt = tid >> 5, n = tid & 31;  // 8 pts x 32 lanes
  const int pid = blockIdx.x * 8 + pt;
  const int b = pid >> 11;
  const int g = n;

  float pr[5][5], cn[5];
#pragma unroll
  for (int d = 0; d < 5; d++) {
    cn[d] = cen2[d * 32 + g];
#pragma unroll
    for (int kk = 0; kk < 5; kk++) pr[d][kk] = prec2[(d * 5 + kk) * 32 + g];
  }

  float4 hv;
  float betaS, sattS;
  {
    int j = idx32[pid * 32 + n];
    int jg = b * NL + j;
    const float* fs = frames + (size_t)pid * 12;
    const float* fj = frames + (size_t)jg * 12;
    float4 A0 = *(const float4*)(fs);
    float4 A2 = *(const float4*)(fs + 8);
    float4 B0 = *(const float4*)(fj);
    float4 B2 = *(const float4*)(fj + 8);
    float dx = B0.x - A0.x, dy = B0.y - A0.y, dzc = B0.z - A0.z;
    float a2x = A2.y, a2y = A2.z, a2z = A2.w;  // z_i
    float zjx = B2.y, zjy = B2.z, zjz = B2.w;
    float dd = dx * dx + dy * dy + dzc * dzc + 1e-12f;
    float dist = sqrtf(dd);
    float zz = a2x * zjx + a2y * zjy + a2z * zjz;
    float dzv = (dx * zjx + dy * zjy + dzc * zjz) / dist;
    float zdv = (a2x * dx + a2y * dy + a2z * dzc) / dist;
    float si = (float)aaidx[pid];
    float sj = (float)aaidx[jg];
    float idist = fminf(fabsf(sj - si), 8.0f);
    float* cr = sCoord + pt * 160 + n * 5;
    cr[0] = dist; cr[1] = zz; cr[2] = dzv; cr[3] = zdv; cr[4] = idist;
    hv = *(const float4*)(head8 + (size_t)jg * 8);  // catt, nf0, nf1
    betaS = head8[(size_t)pid * 8 + 4];
    sattS = head8[(size_t)pid * 8 + 5];
  }
  __syncthreads();
  {
#pragma unroll 8
    for (int i = 0; i < 32; i++) {
      const float* cr = sCoord + pt * 160 + i * 5;
      float df[5];
#pragma unroll
      for (int d = 0; d < 5; d++) df[d] = cr[d] - cn[d];
      float s = 0.0f;
#pragma unroll
      for (int kk = 0; kk < 5; kk++) {
        float y = 0.0f;
#pragma unroll
        for (int d = 0; d < 5; d++) y = fmaf(df[d], pr[d][kk], y);
        s = fmaf(y, y, s);
      }
      sG2[pt * 1056 + i * 33 + g] = __expf(-0.5f * s);
    }
  }
  __syncthreads();
  {
    float gw = emb2B[0];
#pragma unroll 8
    for (int gg = 0; gg < 32; gg++)
      gw = fmaf(sG2[pt * 1056 + n * 33 + gg], emb2W[gg], gw);
    gw = fmaxf(gw, 0.0f);
    float e = (n == 0) ? sattS : hv.x;
    float logit = betaS * e;
    float mx = logit;
#pragma unroll
    for (int d = 1; d < 32; d <<= 1) mx = fmaxf(mx, __shfl_xor(mx, d, 64));
    float wv = gw * __expf(logit - mx);
    float S = wv;
#pragma unroll
    for (int d = 1; d < 32; d <<= 1) S += __shfl_xor(S, d, 64);
    float a = wv / (S + 1e-6f);
    float o0 = a * hv.y, o1 = a * hv.z;
#pragma unroll
    for (int d = 1; d < 32; d <<= 1) {
      o0 += __shfl_xor(o0, d, 64);
      o1 += __shfl_xor(o1, d, 64);
    }
    if (n == 0) {
      out[pid * 2 + 0] = o0;
      out[pid * 2 + 1] = o1;
    }
  }
}

// ---------------------------------------------------------------------------
extern "C" void kernel_launch(void* const* d_in, const int* in_sizes, int n_in,
                              void* d_out, int out_size, void* d_ws, size_t ws_size,
                              hipStream_t stream) {
  const float* attrs = (const float*)d_in[0];
  const float* frames = (const float*)d_in[1];
  const int* aaidx = (const int*)d_in[2];
  const float* cen1 = (const float*)d_in[3];
  const float* prec1 = (const float*)d_in[4];
  const float* opW = (const float*)d_in[5];
  const float* opB = (const float*)d_in[6];
  const float* embW = (const float*)d_in[7];
  const float* embB = (const float*)d_in[8];
  const float* betaW = (const float*)d_in[9];
  const float* betaB = (const float*)d_in[10];
  const float* sattW = (const float*)d_in[11];
  const float* sattB = (const float*)d_in[12];
  const float* cattW = (const float*)d_in[13];
  const float* cattB = (const float*)d_in[14];
  const float* nodW = (const float*)d_in[15];
  const float* nodB = (const float*)d_in[16];
  const float* cen2 = (const float*)d_in[17];
  const float* prec2 = (const float*)d_in[18];
  const float* emb2W = (const float*)d_in[19];
  const float* emb2B = (const float*)d_in[20];
  float* out = (float*)d_out;

  char* ws = (char*)d_ws;
  int* idx32 = (int*)ws;                              // 2 MiB
  u16* outer_bf = (u16*)(ws + 2097152);               // 16384*640*2 = 20 MiB
  float* head8 = (float*)(ws + 23068672);             // 512 KiB
  u16* opWt = (u16*)(ws + 23592960);                  // 160 KiB
  u16* embWt = (u16*)(ws + 23756800);                 // 8 KiB
  float* w5 = (float*)(ws + 23764992);                // 1 KiB
  float* b5 = (float*)(ws + 23766016);                // 32 B

  knn_s1_prep_kernel<<<dim3(2059), dim3(512), 0, stream>>>(
      frames, attrs, aaidx, cen1, prec1, idx32, outer_bf, opW, embW, betaW,
      sattW, cattW, nodW, betaB, sattB, cattB, nodB, opWt, embWt, w5, b5);
  gemm_kernel<<<dim3(512), dim3(256), 0, stream>>>(outer_bf, opWt, opB, embWt,
                                                   embB, w5, b5, head8);
  stage2_kernel<<<dim3(2048), dim3(256), 0, stream>>>(frames, aaidx, cen2, prec2,
                                                      emb2W, emb2B, idx32, head8, out);
}